// Round 19
// baseline (149.471 us; speedup 1.0000x reference)
//
#include <hip/hip_runtime.h>
#include <hip/hip_bf16.h>

#define N_NODES 50000
#define N_EDGES 800000
#define DIM 128
#define NUM_GRAPHS 128
#define BN_EPS 1e-5f

constexpr int BK     = 7;                               // nodes-per-bucket log2
constexpr int NBUCK  = (N_NODES + 127) >> BK;           // 391
constexpr int TILE   = 4096;                            // edges per scatter tile
constexpr int NTILE  = (N_EDGES + TILE - 1) / TILE;     // 196
constexpr int CAP    = 4096;                            // bucket capacity incl. padding
constexpr int NPAD   = N_NODES;                         // zero-row index for padding

constexpr int XCONV  = 3125;                            // x-convert blocks (512 thr)
constexpr int WCONV  = 128;                             // weight-convert blocks
constexpr int PREP_GRID = NTILE + XCONV + WCONV + 1;    // 3450

typedef __attribute__((ext_vector_type(8))) short short8;
typedef __attribute__((ext_vector_type(4))) float f32x4;

__device__ __forceinline__ unsigned short f2bu(float v)
{
    __hip_bfloat16 h = __float2bfloat16(v);
    unsigned short u;
    __builtin_memcpy(&u, &h, 2);
    return u;
}
__device__ __forceinline__ float lo2f(unsigned int v)
{
    return __builtin_bit_cast(float, v << 16);
}
__device__ __forceinline__ float hi2f(unsigned int v)
{
    return __builtin_bit_cast(float, v & 0xffff0000u);
}
__device__ __forceinline__ float b2f(unsigned short u)
{
    return __builtin_bit_cast(float, ((unsigned int)u) << 16);
}

// ---------------------------------------------------------------------------
// PREP: block-range-partitioned INDEPENDENT work (no sync needed):
//   blocks [0, NTILE): fixed-stride bucket scatter (bcur pre-zeroed by memset)
//   blocks [NTILE, NTILE+XCONV): x -> bf16
//   blocks [.., +WCONV): transposed bf16 weights
//   last block: zero pad rows of xb/Hb
// ---------------------------------------------------------------------------
__global__ __launch_bounds__(512)
void prep_kernel(const float* __restrict__ x, __hip_bfloat16* __restrict__ xb,
                 const float* __restrict__ w0, const float* __restrict__ w1,
                 const float* __restrict__ w2, const float* __restrict__ w3,
                 __hip_bfloat16* __restrict__ wt,
                 __hip_bfloat16* __restrict__ Hb,
                 const int* __restrict__ src, const int* __restrict__ dst,
                 int* __restrict__ bcur, unsigned int* __restrict__ bedge)
{
    __shared__ int h[512];
    __shared__ int s[512];
    __shared__ int lofs[512];
    __shared__ int cur[512];
    __shared__ int gofs[512];
    __shared__ unsigned int stage[TILE];

    const int b = blockIdx.x;
    const int t = threadIdx.x;

    if (b < NTILE) {
        // ---- bucket scatter (verified round 10/11 design) ----
        h[t] = 0;
        __syncthreads();

        int e0 = b * TILE;
        for (int i = t; i < TILE; i += 512) {
            int e = e0 + i;
            if (e < N_EDGES) atomicAdd(&h[dst[e] >> BK], 1);
        }
        __syncthreads();

        int v = h[t];
        s[t] = v;
        __syncthreads();
        for (int o = 1; o < 512; o <<= 1) {
            int a = (t >= o) ? s[t - o] : 0;
            __syncthreads();
            s[t] += a;
            __syncthreads();
        }
        int excl = s[t] - v;
        lofs[t] = excl;
        cur[t]  = excl;
        if (t < NBUCK)
            gofs[t] = v ? atomicAdd(&bcur[t], v) : 0;
        __syncthreads();

        const int mtot = s[511];

        for (int i = t; i < TILE; i += 512) {
            int e = e0 + i;
            if (e < N_EDGES) {
                int d = dst[e];
                int bb = d >> BK;
                int r = atomicAdd(&cur[bb], 1);
                stage[r] = (unsigned int)src[e]
                         | ((unsigned int)(d & 127) << 16)
                         | ((unsigned int)bb << 23);
            }
        }
        __syncthreads();

        for (int i = t; i < mtot; i += 512) {
            unsigned int w = stage[i];
            int bb = (int)(w >> 23);
            int pos = gofs[bb] + (i - lofs[bb]);
            if (pos < CAP)                              // overflow guard (never fires)
                bedge[(size_t)bb * CAP + pos] = w & 0x7fffffu;
        }
    } else if (b < NTILE + XCONV) {
        // ---- x -> bf16 (512 float4 groups per block) ----
        size_t i = ((size_t)(b - NTILE) * 512 + t) * 4;
        float4 v = *reinterpret_cast<const float4*>(x + i);
        uint2 o;
        o.x = (unsigned int)f2bu(v.x) | ((unsigned int)f2bu(v.y) << 16);
        o.y = (unsigned int)f2bu(v.z) | ((unsigned int)f2bu(v.w) << 16);
        *reinterpret_cast<uint2*>(reinterpret_cast<unsigned short*>(xb) + i) = o;
    } else if (b < NTILE + XCONV + WCONV) {
        // ---- transposed bf16 weights ----
        int o = (b - NTILE - XCONV) * 512 + t;          // 65536
        int m = o >> 14, idx = o & 16383;
        const float* W = (m == 0) ? w0 : (m == 1) ? w1 : (m == 2) ? w2 : w3;
        int n = idx >> 7, k = idx & 127;
        wt[o] = __float2bfloat16(W[k * 128 + n]);
    } else {
        // ---- zero the NPAD pad rows ----
        if (t < DIM) {
            xb[(size_t)NPAD * DIM + t] = __float2bfloat16(0.f);
            Hb[(size_t)NPAD * DIM + t] = __float2bfloat16(0.f);
        }
    }
}

// ---------------------------------------------------------------------------
// per-bucket CSR finalize (padded x16 with NPAD entries) + G zeroing
// (blocks 0..NUM_GRAPHS-1 also zero their G row; G first read in mlp<1>).
// ---------------------------------------------------------------------------
__global__ __launch_bounds__(256)
void bcsr_kernel(const unsigned int* __restrict__ bedge,
                 const int* __restrict__ bcur,
                 int* __restrict__ rowbeg, int* __restrict__ rowend,
                 unsigned short* __restrict__ elist,
                 float* __restrict__ G)
{
    __shared__ int h2[128];     // real counts
    __shared__ int sc[128];     // scan of padded counts
    __shared__ int cur[128];

    int b  = blockIdx.x;
    int t  = threadIdx.x;

    if (b < NUM_GRAPHS && t < DIM)
        G[b * DIM + t] = 0.f;

    int m  = bcur[b];
    if (m > CAP) m = CAP;
    const int e0 = b * CAP;
    const unsigned int* be = bedge + (size_t)e0;

    if (t < 128) h2[t] = 0;
    __syncthreads();
    for (int i = t; i < m; i += 256)
        atomicAdd(&h2[(be[i] >> 16) & 127], 1);
    __syncthreads();

    int pc = 0;
    if (t < 128) {
        pc = (h2[t] + 15) & ~15;          // padded count
        sc[t] = pc;
    }
    __syncthreads();
    for (int o = 1; o < 128; o <<= 1) {
        int a = 0;
        if (t < 128 && t >= o) a = sc[t - o];
        __syncthreads();
        if (t < 128) sc[t] += a;
        __syncthreads();
    }
    if (t < 128) {
        int ex = sc[t] - pc;
        int node = (b << BK) + t;
        if (node < N_NODES) {
            rowbeg[node] = e0 + ex;
            rowend[node] = e0 + ex + pc;
        }
        cur[t] = ex;
        int cnt = h2[t];
        for (int i = ex + cnt; i < ex + pc && i < CAP; ++i)
            elist[e0 + i] = (unsigned short)NPAD;
    }
    __syncthreads();

    for (int i = t; i < m; i += 256) {
        unsigned int w = be[i];
        int n = (int)((w >> 16) & 127);
        int r = atomicAdd(&cur[n], 1);
        if (r < CAP)
            elist[e0 + r] = (unsigned short)(w & 0xffffu);
    }
}

// ---------------------------------------------------------------------------
// gather-aggregate, CHANNEL-SLICED for XCD L2 locality:
//   blockIdx = quad*2 + slab; slab in {0,1} = half-row (64 ch = 8 uint4).
//   With round-robin blockIdx%8 XCD mapping, slab 0 runs on even XCDs and
//   slab 1 on odd -> per-XCD read working set = 50000 x 128B = 6.4 MB
//   (was 12.8 MB) -> higher L2 hit rate, ~half the LLC traffic.
//   Wave per node: lane = (slot s = l>>3, group g = l&7); one dwordx4 load
//   covers 8 edges x 128B; main loop 32 edges = 4 loads in flight/lane.
//   Padded x16 edge lists -> remainder after the 32-loop is exactly {0,16}.
// ---------------------------------------------------------------------------
__device__ __forceinline__ void accum8(float* acc, uint4 v)
{
    acc[0] += lo2f(v.x); acc[1] += hi2f(v.x);
    acc[2] += lo2f(v.y); acc[3] += hi2f(v.y);
    acc[4] += lo2f(v.z); acc[5] += hi2f(v.z);
    acc[6] += lo2f(v.w); acc[7] += hi2f(v.w);
}

__global__ __launch_bounds__(256)
void gather_agg_kernel(const __hip_bfloat16* __restrict__ feat,
                       const int* __restrict__ rowbeg,
                       const int* __restrict__ rowend,
                       const unsigned short* __restrict__ elist,
                       __hip_bfloat16* __restrict__ out)
{
    const int slab = blockIdx.x & 1;
    const int quad = blockIdx.x >> 1;
    const int node = quad * 4 + (threadIdx.x >> 6);
    const int l = threadIdx.x & 63;
    const int g = l & 7;                // uint4 group within slab
    const int s = l >> 3;               // edge slot 0..7
    const int go = slab * 8 + g;        // uint4 index within row
    const uint4* F = reinterpret_cast<const uint4*>(feat);

    int p = rowbeg[node];
    const int e = rowend[node];

    float acc[8] = {};
    if (s == 0)
        accum8(acc, F[(size_t)node * 16 + go]);

    for (; p + 32 <= e; p += 32) {
        int i0 = elist[p + s];
        int i1 = elist[p + 8 + s];
        int i2 = elist[p + 16 + s];
        int i3 = elist[p + 24 + s];
        uint4 v0 = F[(size_t)i0 * 16 + go];
        uint4 v1 = F[(size_t)i1 * 16 + go];
        uint4 v2 = F[(size_t)i2 * 16 + go];
        uint4 v3 = F[(size_t)i3 * 16 + go];
        accum8(acc, v0);
        accum8(acc, v1);
        accum8(acc, v2);
        accum8(acc, v3);
    }
    if (p < e) {                        // exactly one 16-chunk remains
        int i0 = elist[p + s];
        int i1 = elist[p + 8 + s];
        uint4 v0 = F[(size_t)i0 * 16 + go];
        uint4 v1 = F[(size_t)i1 * 16 + go];
        accum8(acc, v0);
        accum8(acc, v1);
    }

    #pragma unroll
    for (int j = 0; j < 8; ++j) {
        acc[j] += __shfl_xor(acc[j], 8);
        acc[j] += __shfl_xor(acc[j], 16);
        acc[j] += __shfl_xor(acc[j], 32);
    }

    if (s == 0) {
        uint4 o;
        o.x = (unsigned int)f2bu(acc[0]) | ((unsigned int)f2bu(acc[1]) << 16);
        o.y = (unsigned int)f2bu(acc[2]) | ((unsigned int)f2bu(acc[3]) << 16);
        o.z = (unsigned int)f2bu(acc[4]) | ((unsigned int)f2bu(acc[5]) << 16);
        o.w = (unsigned int)f2bu(acc[6]) | ((unsigned int)f2bu(acc[7]) << 16);
        reinterpret_cast<uint4*>(out)[(size_t)node * 16 + go] = o;
    }
}

// ---------------------------------------------------------------------------
// Fused GIN MLP: out = relu( relu(BN(A @ W1 + b1)) @ W2 + b2 )
// MFMA 16x16x32, W in LDS, t1 in LDS (verified round 4-16).
// POOL=1: segment-sum the block's 64 h2 rows by sorted batch id, atomicAdd
// f32 partials into G (h2 never hits global).
// ---------------------------------------------------------------------------
template<int POOL>
__global__ __launch_bounds__(256)
void mlp_kernel(const __hip_bfloat16* __restrict__ A,
                const __hip_bfloat16* __restrict__ W1t,
                const __hip_bfloat16* __restrict__ W2t,
                const float* __restrict__ b1,
                const float* __restrict__ bng, const float* __restrict__ bnb,
                const float* __restrict__ bnm, const float* __restrict__ bnv,
                const float* __restrict__ b2,
                __hip_bfloat16* __restrict__ out,
                const int* __restrict__ batch, float* __restrict__ G,
                int M)
{
    __shared__ __align__(16) short sW[128 * 136];   // 34.8 KB
    __shared__ __align__(16) short sT[64 * 136];    // 17.4 KB

    const int t    = threadIdx.x;
    const int w    = t >> 6;
    const int l    = t & 63;
    const int lr   = l & 15;
    const int lk   = (l >> 4) << 3;
    const int orow = (l >> 4) << 2;
    const int row0b = blockIdx.x * 64;
    const int row0 = row0b + w * 16;

    const short* w1s = reinterpret_cast<const short*>(W1t);
    #pragma unroll
    for (int i = t; i < 2048; i += 256) {
        int r = i >> 4, c8 = (i & 15) << 3;
        *reinterpret_cast<short8*>(&sW[r * 136 + c8]) =
            *reinterpret_cast<const short8*>(&w1s[r * 128 + c8]);
    }

    float sc1[8], sh1[8];
    #pragma unroll
    for (int ct = 0; ct < 8; ++ct) {
        int c = ct * 16 + lr;
        float s = bng[c] * rsqrtf(bnv[c] + BN_EPS);
        sc1[ct] = s;
        sh1[ct] = (b1[c] - bnm[c]) * s + bnb[c];
    }

    const short* Ab = reinterpret_cast<const short*>(A);
    const int arow = row0 + lr;
    short8 af[4];
    #pragma unroll
    for (int ks = 0; ks < 4; ++ks) {
        short8 z = {};
        af[ks] = (arow < M)
            ? *reinterpret_cast<const short8*>(Ab + (size_t)arow * DIM + ks * 32 + lk)
            : z;
    }

    __syncthreads();

    f32x4 acc[8] = {};
    #pragma unroll
    for (int ks = 0; ks < 4; ++ks) {
        #pragma unroll
        for (int ct = 0; ct < 8; ++ct) {
            short8 bf = *reinterpret_cast<const short8*>(
                &sW[(ct * 16 + lr) * 136 + ks * 32 + lk]);
            acc[ct] = __builtin_amdgcn_mfma_f32_16x16x32_bf16(af[ks], bf, acc[ct], 0, 0, 0);
        }
    }

    #pragma unroll
    for (int ct = 0; ct < 8; ++ct) {
        #pragma unroll
        for (int q = 0; q < 4; ++q) {
            float v = fmaxf(acc[ct][q] * sc1[ct] + sh1[ct], 0.f);
            sT[(w * 16 + orow + q) * 136 + ct * 16 + lr] = (short)f2bu(v);
        }
    }

    __syncthreads();
    const short* w2s = reinterpret_cast<const short*>(W2t);
    #pragma unroll
    for (int i = t; i < 2048; i += 256) {
        int r = i >> 4, c8 = (i & 15) << 3;
        *reinterpret_cast<short8*>(&sW[r * 136 + c8]) =
            *reinterpret_cast<const short8*>(&w2s[r * 128 + c8]);
    }
    __syncthreads();

    f32x4 acc2[8] = {};
    #pragma unroll
    for (int ks = 0; ks < 4; ++ks) {
        short8 tf = *reinterpret_cast<const short8*>(
            &sT[(w * 16 + lr) * 136 + ks * 32 + lk]);
        #pragma unroll
        for (int ct = 0; ct < 8; ++ct) {
            short8 bf = *reinterpret_cast<const short8*>(
                &sW[(ct * 16 + lr) * 136 + ks * 32 + lk]);
            acc2[ct] = __builtin_amdgcn_mfma_f32_16x16x32_bf16(tf, bf, acc2[ct], 0, 0, 0);
        }
    }

    if constexpr (!POOL) {
        #pragma unroll
        for (int ct = 0; ct < 8; ++ct) {
            float bi = b2[ct * 16 + lr];
            #pragma unroll
            for (int q = 0; q < 4; ++q) {
                int r = row0 + orow + q;
                if (r < M) {
                    float v = fmaxf(acc2[ct][q] + bi, 0.f);
                    out[(size_t)r * DIM + ct * 16 + lr] = __float2bfloat16(v);
                }
            }
        }
    } else {
        #pragma unroll
        for (int ct = 0; ct < 8; ++ct) {
            float bi = b2[ct * 16 + lr];
            #pragma unroll
            for (int q = 0; q < 4; ++q) {
                float v = fmaxf(acc2[ct][q] + bi, 0.f);
                sT[(w * 16 + orow + q) * 136 + ct * 16 + lr] = (short)f2bu(v);
            }
        }
        __syncthreads();
        const int c  = t & 127;
        const int rh = t >> 7;
        float run = 0.f;
        int gcur = -1;
        for (int r = rh * 32; r < rh * 32 + 32; ++r) {
            int node = row0b + r;
            if (node >= M) break;
            int gb = batch[node];
            if (gb != gcur) {
                if (gcur >= 0 && run != 0.f) atomicAdd(&G[gcur * DIM + c], run);
                gcur = gb;
                run = 0.f;
            }
            run += b2f((unsigned short)sT[r * 136 + c]);
        }
        if (gcur >= 0 && run != 0.f) atomicAdd(&G[gcur * DIM + c], run);
    }
}

// ---------------------------------------------------------------------------
// fused head, PARALLEL: one block per graph (verified round 10-16)
// ---------------------------------------------------------------------------
__global__ __launch_bounds__(128)
void head_kernel(const float* __restrict__ G,
                 const float* __restrict__ w1, const float* __restrict__ b1f,
                 const float* __restrict__ w2, const float* __restrict__ b2f,
                 float* __restrict__ out)
{
    __shared__ float sg[DIM];
    __shared__ float r0[DIM], r1[DIM];
    const int r = blockIdx.x;
    const int c = threadIdx.x;

    sg[c] = G[r * DIM + c];
    __syncthreads();

    float a = b1f[c];
    #pragma unroll 8
    for (int k = 0; k < DIM; ++k)
        a = fmaf(sg[k], w1[k * DIM + c], a);
    float g2 = fmaxf(a, 0.f);
    r0[c] = g2 * w2[c * 2];
    r1[c] = g2 * w2[c * 2 + 1];
    __syncthreads();

    for (int off = 64; off > 0; off >>= 1) {
        if (c < off) { r0[c] += r0[c + off]; r1[c] += r1[c + off]; }
        __syncthreads();
    }
    if (c == 0) {
        out[r * 2]     = r0[0] + b2f[0];
        out[r * 2 + 1] = r1[0] + b2f[1];
    }
}

// ---------------------------------------------------------------------------
extern "C" void kernel_launch(void* const* d_in, const int* in_sizes, int n_in,
                              void* d_out, int out_size, void* d_ws, size_t ws_size,
                              hipStream_t stream)
{
    const float* x    = (const float*)d_in[0];
    const int*   ei   = (const int*)d_in[1];
    const int*   src  = ei;
    const int*   dst  = ei + N_EDGES;
    const int*   batch= (const int*)d_in[2];
    const float* w1_1 = (const float*)d_in[3];
    const float* b1_1 = (const float*)d_in[4];
    const float* bn1g = (const float*)d_in[5];
    const float* bn1b = (const float*)d_in[6];
    const float* bn1m = (const float*)d_in[7];
    const float* bn1v = (const float*)d_in[8];
    const float* w1_2 = (const float*)d_in[9];
    const float* b1_2 = (const float*)d_in[10];
    const float* w2_1 = (const float*)d_in[11];
    const float* b2_1 = (const float*)d_in[12];
    const float* bn2g = (const float*)d_in[13];
    const float* bn2b = (const float*)d_in[14];
    const float* bn2m = (const float*)d_in[15];
    const float* bn2v = (const float*)d_in[16];
    const float* w2_2 = (const float*)d_in[17];
    const float* b2_2 = (const float*)d_in[18];
    const float* lin1w= (const float*)d_in[19];
    const float* lin1b= (const float*)d_in[20];
    const float* lin2w= (const float*)d_in[21];
    const float* lin2b= (const float*)d_in[22];

    const size_t NBE  = (size_t)N_NODES * DIM;     // 6.4M
    const size_t NBEP = NBE + DIM;                 // + zero pad row
    __hip_bfloat16* xb = (__hip_bfloat16*)d_ws;    // NBEP bf16
    __hip_bfloat16* Ab = xb + NBEP;                // NBE bf16 (agg)
    __hip_bfloat16* Hb = Ab + NBE;                 // NBEP bf16 (mlp1 out)
    __hip_bfloat16* Wt = Hb + NBEP;                // 4 * 16384 bf16
    float* G  = (float*)(Wt + 4 * 16384);
    int* rowbeg = (int*)(G + NUM_GRAPHS * DIM);    // N_NODES
    int* rowend = rowbeg + N_NODES;                // N_NODES
    int* bcur   = rowend + N_NODES;                // NBUCK
    unsigned int* bedge = (unsigned int*)(bcur + NBUCK + 1);       // NBUCK*CAP
    unsigned short* elist = (unsigned short*)(bedge + (size_t)NBUCK * CAP);

    const int gather_grid = (N_NODES / 4) * 2;         // 25000 (quad x slab)
    const int mlp_grid    = (N_NODES + 63) / 64;       // 782

    // ---- 0: zero bucket cursors (1.6 KB) ----
    hipMemsetAsync(bcur, 0, NBUCK * sizeof(int), stream);

    // ---- 1: prep (scatter || x-convert || w-convert || pad-zero) ----
    prep_kernel<<<PREP_GRID, 512, 0, stream>>>(
        x, xb, w1_1, w1_2, w2_1, w2_2, Wt, Hb, src, dst, bcur, bedge);

    // ---- 2: padded CSR finalize (+ G zeroing) ----
    bcsr_kernel<<<NBUCK, 256, 0, stream>>>(bedge, bcur, rowbeg, rowend, elist, G);

    // ---- 3-4: conv1 ----
    gather_agg_kernel<<<gather_grid, 256, 0, stream>>>(xb, rowbeg, rowend, elist, Ab);
    mlp_kernel<0><<<mlp_grid, 256, 0, stream>>>(
        Ab, Wt, Wt + 16384, b1_1, bn1g, bn1b, bn1m, bn1v, b1_2, Hb,
        batch, G, N_NODES);

    // ---- 5-6: conv2 (pool fused into MLP epilogue) ----
    gather_agg_kernel<<<gather_grid, 256, 0, stream>>>(Hb, rowbeg, rowend, elist, Ab);
    mlp_kernel<1><<<mlp_grid, 256, 0, stream>>>(
        Ab, Wt + 2 * 16384, Wt + 3 * 16384, b2_1, bn2g, bn2b, bn2m, bn2v, b2_2,
        (__hip_bfloat16*)nullptr, batch, G, N_NODES);

    // ---- 7: head ----
    head_kernel<<<NUM_GRAPHS, 128, 0, stream>>>(
        G, lin1w, lin1b, lin2w, lin2b, (float*)d_out);
}

// Round 20
// 140.429 us; speedup vs baseline: 1.0644x; 1.0644x over previous
//
#include <hip/hip_runtime.h>
#include <hip/hip_bf16.h>

#define N_NODES 50000
#define N_EDGES 800000
#define DIM 128
#define NUM_GRAPHS 128
#define BN_EPS 1e-5f

constexpr int BK     = 7;                               // nodes-per-bucket log2
constexpr int NBUCK  = (N_NODES + 127) >> BK;           // 391
constexpr int TILE   = 4096;                            // edges per scatter tile
constexpr int NTILE  = (N_EDGES + TILE - 1) / TILE;     // 196
constexpr int CAP    = 4096;                            // bucket capacity incl. padding
constexpr int NPAD   = N_NODES;                         // zero-row index for padding

constexpr int XCONV  = 3125;                            // x-convert blocks (512 thr)
constexpr int WCONV  = 128;                             // weight-convert blocks
constexpr int PREP_GRID = NTILE + XCONV + WCONV + 1;    // 3450

typedef __attribute__((ext_vector_type(8))) short short8;
typedef __attribute__((ext_vector_type(4))) float f32x4;

__device__ __forceinline__ unsigned short f2bu(float v)
{
    __hip_bfloat16 h = __float2bfloat16(v);
    unsigned short u;
    __builtin_memcpy(&u, &h, 2);
    return u;
}
__device__ __forceinline__ float lo2f(unsigned int v)
{
    return __builtin_bit_cast(float, v << 16);
}
__device__ __forceinline__ float hi2f(unsigned int v)
{
    return __builtin_bit_cast(float, v & 0xffff0000u);
}
__device__ __forceinline__ float b2f(unsigned short u)
{
    return __builtin_bit_cast(float, ((unsigned int)u) << 16);
}

// ---------------------------------------------------------------------------
// PREP: block-range-partitioned INDEPENDENT work (no sync needed):
//   blocks [0, NTILE): fixed-stride bucket scatter (bcur pre-zeroed by memset)
//   blocks [NTILE, NTILE+XCONV): x -> bf16
//   blocks [.., +WCONV): transposed bf16 weights
//   last block: zero pad rows of xb/Hb
// ---------------------------------------------------------------------------
__global__ __launch_bounds__(512)
void prep_kernel(const float* __restrict__ x, __hip_bfloat16* __restrict__ xb,
                 const float* __restrict__ w0, const float* __restrict__ w1,
                 const float* __restrict__ w2, const float* __restrict__ w3,
                 __hip_bfloat16* __restrict__ wt,
                 __hip_bfloat16* __restrict__ Hb,
                 const int* __restrict__ src, const int* __restrict__ dst,
                 int* __restrict__ bcur, unsigned int* __restrict__ bedge)
{
    __shared__ int h[512];
    __shared__ int s[512];
    __shared__ int lofs[512];
    __shared__ int cur[512];
    __shared__ int gofs[512];
    __shared__ unsigned int stage[TILE];

    const int b = blockIdx.x;
    const int t = threadIdx.x;

    if (b < NTILE) {
        // ---- bucket scatter (verified round 10/11 design) ----
        h[t] = 0;
        __syncthreads();

        int e0 = b * TILE;
        for (int i = t; i < TILE; i += 512) {
            int e = e0 + i;
            if (e < N_EDGES) atomicAdd(&h[dst[e] >> BK], 1);
        }
        __syncthreads();

        int v = h[t];
        s[t] = v;
        __syncthreads();
        for (int o = 1; o < 512; o <<= 1) {
            int a = (t >= o) ? s[t - o] : 0;
            __syncthreads();
            s[t] += a;
            __syncthreads();
        }
        int excl = s[t] - v;
        lofs[t] = excl;
        cur[t]  = excl;
        if (t < NBUCK)
            gofs[t] = v ? atomicAdd(&bcur[t], v) : 0;
        __syncthreads();

        const int mtot = s[511];

        for (int i = t; i < TILE; i += 512) {
            int e = e0 + i;
            if (e < N_EDGES) {
                int d = dst[e];
                int bb = d >> BK;
                int r = atomicAdd(&cur[bb], 1);
                stage[r] = (unsigned int)src[e]
                         | ((unsigned int)(d & 127) << 16)
                         | ((unsigned int)bb << 23);
            }
        }
        __syncthreads();

        for (int i = t; i < mtot; i += 512) {
            unsigned int w = stage[i];
            int bb = (int)(w >> 23);
            int pos = gofs[bb] + (i - lofs[bb]);
            if (pos < CAP)                              // overflow guard (never fires)
                bedge[(size_t)bb * CAP + pos] = w & 0x7fffffu;
        }
    } else if (b < NTILE + XCONV) {
        // ---- x -> bf16 (512 float4 groups per block) ----
        size_t i = ((size_t)(b - NTILE) * 512 + t) * 4;
        float4 v = *reinterpret_cast<const float4*>(x + i);
        uint2 o;
        o.x = (unsigned int)f2bu(v.x) | ((unsigned int)f2bu(v.y) << 16);
        o.y = (unsigned int)f2bu(v.z) | ((unsigned int)f2bu(v.w) << 16);
        *reinterpret_cast<uint2*>(reinterpret_cast<unsigned short*>(xb) + i) = o;
    } else if (b < NTILE + XCONV + WCONV) {
        // ---- transposed bf16 weights ----
        int o = (b - NTILE - XCONV) * 512 + t;          // 65536
        int m = o >> 14, idx = o & 16383;
        const float* W = (m == 0) ? w0 : (m == 1) ? w1 : (m == 2) ? w2 : w3;
        int n = idx >> 7, k = idx & 127;
        wt[o] = __float2bfloat16(W[k * 128 + n]);
    } else {
        // ---- zero the NPAD pad rows ----
        if (t < DIM) {
            xb[(size_t)NPAD * DIM + t] = __float2bfloat16(0.f);
            Hb[(size_t)NPAD * DIM + t] = __float2bfloat16(0.f);
        }
    }
}

// ---------------------------------------------------------------------------
// per-bucket CSR finalize (padded x16 with NPAD entries) + G zeroing
// (blocks 0..NUM_GRAPHS-1 also zero their G row; G first read in mlp<1>).
// ---------------------------------------------------------------------------
__global__ __launch_bounds__(256)
void bcsr_kernel(const unsigned int* __restrict__ bedge,
                 const int* __restrict__ bcur,
                 int* __restrict__ rowbeg, int* __restrict__ rowend,
                 unsigned short* __restrict__ elist,
                 float* __restrict__ G)
{
    __shared__ int h2[128];     // real counts
    __shared__ int sc[128];     // scan of padded counts
    __shared__ int cur[128];

    int b  = blockIdx.x;
    int t  = threadIdx.x;

    if (b < NUM_GRAPHS && t < DIM)
        G[b * DIM + t] = 0.f;

    int m  = bcur[b];
    if (m > CAP) m = CAP;
    const int e0 = b * CAP;
    const unsigned int* be = bedge + (size_t)e0;

    if (t < 128) h2[t] = 0;
    __syncthreads();
    for (int i = t; i < m; i += 256)
        atomicAdd(&h2[(be[i] >> 16) & 127], 1);
    __syncthreads();

    int pc = 0;
    if (t < 128) {
        pc = (h2[t] + 15) & ~15;          // padded count
        sc[t] = pc;
    }
    __syncthreads();
    for (int o = 1; o < 128; o <<= 1) {
        int a = 0;
        if (t < 128 && t >= o) a = sc[t - o];
        __syncthreads();
        if (t < 128) sc[t] += a;
        __syncthreads();
    }
    if (t < 128) {
        int ex = sc[t] - pc;
        int node = (b << BK) + t;
        if (node < N_NODES) {
            rowbeg[node] = e0 + ex;
            rowend[node] = e0 + ex + pc;
        }
        cur[t] = ex;
        int cnt = h2[t];
        for (int i = ex + cnt; i < ex + pc && i < CAP; ++i)
            elist[e0 + i] = (unsigned short)NPAD;
    }
    __syncthreads();

    for (int i = t; i < m; i += 256) {
        unsigned int w = be[i];
        int n = (int)((w >> 16) & 127);
        int r = atomicAdd(&cur[n], 1);
        if (r < CAP)
            elist[e0 + r] = (unsigned short)(w & 0xffffu);
    }
}

// ---------------------------------------------------------------------------
// gather-aggregate (uint4 = 16B/lane). One WAVE per node (verified r9-r16):
// padded x16 edge lists -> uniform 32/16-edge chunks, no tails.
// ---------------------------------------------------------------------------
__device__ __forceinline__ void accum8(float* acc, uint4 v)
{
    acc[0] += lo2f(v.x); acc[1] += hi2f(v.x);
    acc[2] += lo2f(v.y); acc[3] += hi2f(v.y);
    acc[4] += lo2f(v.z); acc[5] += hi2f(v.z);
    acc[6] += lo2f(v.w); acc[7] += hi2f(v.w);
}

__global__ __launch_bounds__(256)
void gather_agg_kernel(const __hip_bfloat16* __restrict__ feat,
                       const int* __restrict__ rowbeg,
                       const int* __restrict__ rowend,
                       const unsigned short* __restrict__ elist,
                       __hip_bfloat16* __restrict__ out)
{
    const int node = blockIdx.x * 4 + (threadIdx.x >> 6);
    const int l = threadIdx.x & 63;
    const int g = l & 15;
    const int s = l >> 4;
    const uint4* F = reinterpret_cast<const uint4*>(feat);

    int p = rowbeg[node];
    const int e = rowend[node];

    float acc[8] = {};
    if (s == 0)
        accum8(acc, F[(size_t)node * 16 + g]);

    for (; p + 32 <= e; p += 32) {
        int i0 = elist[p + s];
        int i1 = elist[p + 4 + s];
        int i2 = elist[p + 8 + s];
        int i3 = elist[p + 12 + s];
        int i4 = elist[p + 16 + s];
        int i5 = elist[p + 20 + s];
        int i6 = elist[p + 24 + s];
        int i7 = elist[p + 28 + s];
        uint4 v0 = F[(size_t)i0 * 16 + g];
        uint4 v1 = F[(size_t)i1 * 16 + g];
        uint4 v2 = F[(size_t)i2 * 16 + g];
        uint4 v3 = F[(size_t)i3 * 16 + g];
        uint4 v4 = F[(size_t)i4 * 16 + g];
        uint4 v5 = F[(size_t)i5 * 16 + g];
        uint4 v6 = F[(size_t)i6 * 16 + g];
        uint4 v7 = F[(size_t)i7 * 16 + g];
        accum8(acc, v0);
        accum8(acc, v1);
        accum8(acc, v2);
        accum8(acc, v3);
        accum8(acc, v4);
        accum8(acc, v5);
        accum8(acc, v6);
        accum8(acc, v7);
    }
    if (p < e) {
        int i0 = elist[p + s];
        int i1 = elist[p + 4 + s];
        int i2 = elist[p + 8 + s];
        int i3 = elist[p + 12 + s];
        uint4 v0 = F[(size_t)i0 * 16 + g];
        uint4 v1 = F[(size_t)i1 * 16 + g];
        uint4 v2 = F[(size_t)i2 * 16 + g];
        uint4 v3 = F[(size_t)i3 * 16 + g];
        accum8(acc, v0);
        accum8(acc, v1);
        accum8(acc, v2);
        accum8(acc, v3);
    }

    #pragma unroll
    for (int j = 0; j < 8; ++j) {
        acc[j] += __shfl_xor(acc[j], 16);
        acc[j] += __shfl_xor(acc[j], 32);
    }

    if (s == 0) {
        uint4 o;
        o.x = (unsigned int)f2bu(acc[0]) | ((unsigned int)f2bu(acc[1]) << 16);
        o.y = (unsigned int)f2bu(acc[2]) | ((unsigned int)f2bu(acc[3]) << 16);
        o.z = (unsigned int)f2bu(acc[4]) | ((unsigned int)f2bu(acc[5]) << 16);
        o.w = (unsigned int)f2bu(acc[6]) | ((unsigned int)f2bu(acc[7]) << 16);
        reinterpret_cast<uint4*>(out)[(size_t)node * 16 + g] = o;
    }
}

// ---------------------------------------------------------------------------
// Fused GIN MLP: out = relu( relu(BN(A @ W1 + b1)) @ W2 + b2 )
// MFMA 16x16x32, W in LDS, t1 in LDS (verified round 4-16).
// POOL=1: segment-sum the block's 64 h2 rows by sorted batch id, atomicAdd
// f32 partials into G (h2 never hits global).
// ---------------------------------------------------------------------------
template<int POOL>
__global__ __launch_bounds__(256)
void mlp_kernel(const __hip_bfloat16* __restrict__ A,
                const __hip_bfloat16* __restrict__ W1t,
                const __hip_bfloat16* __restrict__ W2t,
                const float* __restrict__ b1,
                const float* __restrict__ bng, const float* __restrict__ bnb,
                const float* __restrict__ bnm, const float* __restrict__ bnv,
                const float* __restrict__ b2,
                __hip_bfloat16* __restrict__ out,
                const int* __restrict__ batch, float* __restrict__ G,
                int M)
{
    __shared__ __align__(16) short sW[128 * 136];   // 34.8 KB
    __shared__ __align__(16) short sT[64 * 136];    // 17.4 KB

    const int t    = threadIdx.x;
    const int w    = t >> 6;
    const int l    = t & 63;
    const int lr   = l & 15;
    const int lk   = (l >> 4) << 3;
    const int orow = (l >> 4) << 2;
    const int row0b = blockIdx.x * 64;
    const int row0 = row0b + w * 16;

    const short* w1s = reinterpret_cast<const short*>(W1t);
    #pragma unroll
    for (int i = t; i < 2048; i += 256) {
        int r = i >> 4, c8 = (i & 15) << 3;
        *reinterpret_cast<short8*>(&sW[r * 136 + c8]) =
            *reinterpret_cast<const short8*>(&w1s[r * 128 + c8]);
    }

    float sc1[8], sh1[8];
    #pragma unroll
    for (int ct = 0; ct < 8; ++ct) {
        int c = ct * 16 + lr;
        float s = bng[c] * rsqrtf(bnv[c] + BN_EPS);
        sc1[ct] = s;
        sh1[ct] = (b1[c] - bnm[c]) * s + bnb[c];
    }

    const short* Ab = reinterpret_cast<const short*>(A);
    const int arow = row0 + lr;
    short8 af[4];
    #pragma unroll
    for (int ks = 0; ks < 4; ++ks) {
        short8 z = {};
        af[ks] = (arow < M)
            ? *reinterpret_cast<const short8*>(Ab + (size_t)arow * DIM + ks * 32 + lk)
            : z;
    }

    __syncthreads();

    f32x4 acc[8] = {};
    #pragma unroll
    for (int ks = 0; ks < 4; ++ks) {
        #pragma unroll
        for (int ct = 0; ct < 8; ++ct) {
            short8 bf = *reinterpret_cast<const short8*>(
                &sW[(ct * 16 + lr) * 136 + ks * 32 + lk]);
            acc[ct] = __builtin_amdgcn_mfma_f32_16x16x32_bf16(af[ks], bf, acc[ct], 0, 0, 0);
        }
    }

    #pragma unroll
    for (int ct = 0; ct < 8; ++ct) {
        #pragma unroll
        for (int q = 0; q < 4; ++q) {
            float v = fmaxf(acc[ct][q] * sc1[ct] + sh1[ct], 0.f);
            sT[(w * 16 + orow + q) * 136 + ct * 16 + lr] = (short)f2bu(v);
        }
    }

    __syncthreads();
    const short* w2s = reinterpret_cast<const short*>(W2t);
    #pragma unroll
    for (int i = t; i < 2048; i += 256) {
        int r = i >> 4, c8 = (i & 15) << 3;
        *reinterpret_cast<short8*>(&sW[r * 136 + c8]) =
            *reinterpret_cast<const short8*>(&w2s[r * 128 + c8]);
    }
    __syncthreads();

    f32x4 acc2[8] = {};
    #pragma unroll
    for (int ks = 0; ks < 4; ++ks) {
        short8 tf = *reinterpret_cast<const short8*>(
            &sT[(w * 16 + lr) * 136 + ks * 32 + lk]);
        #pragma unroll
        for (int ct = 0; ct < 8; ++ct) {
            short8 bf = *reinterpret_cast<const short8*>(
                &sW[(ct * 16 + lr) * 136 + ks * 32 + lk]);
            acc2[ct] = __builtin_amdgcn_mfma_f32_16x16x32_bf16(tf, bf, acc2[ct], 0, 0, 0);
        }
    }

    if constexpr (!POOL) {
        #pragma unroll
        for (int ct = 0; ct < 8; ++ct) {
            float bi = b2[ct * 16 + lr];
            #pragma unroll
            for (int q = 0; q < 4; ++q) {
                int r = row0 + orow + q;
                if (r < M) {
                    float v = fmaxf(acc2[ct][q] + bi, 0.f);
                    out[(size_t)r * DIM + ct * 16 + lr] = __float2bfloat16(v);
                }
            }
        }
    } else {
        #pragma unroll
        for (int ct = 0; ct < 8; ++ct) {
            float bi = b2[ct * 16 + lr];
            #pragma unroll
            for (int q = 0; q < 4; ++q) {
                float v = fmaxf(acc2[ct][q] + bi, 0.f);
                sT[(w * 16 + orow + q) * 136 + ct * 16 + lr] = (short)f2bu(v);
            }
        }
        __syncthreads();
        const int c  = t & 127;
        const int rh = t >> 7;
        float run = 0.f;
        int gcur = -1;
        for (int r = rh * 32; r < rh * 32 + 32; ++r) {
            int node = row0b + r;
            if (node >= M) break;
            int gb = batch[node];
            if (gb != gcur) {
                if (gcur >= 0 && run != 0.f) atomicAdd(&G[gcur * DIM + c], run);
                gcur = gb;
                run = 0.f;
            }
            run += b2f((unsigned short)sT[r * 136 + c]);
        }
        if (gcur >= 0 && run != 0.f) atomicAdd(&G[gcur * DIM + c], run);
    }
}

// ---------------------------------------------------------------------------
// fused head, PARALLEL: one block per graph (verified round 10-16)
// ---------------------------------------------------------------------------
__global__ __launch_bounds__(128)
void head_kernel(const float* __restrict__ G,
                 const float* __restrict__ w1, const float* __restrict__ b1f,
                 const float* __restrict__ w2, const float* __restrict__ b2f,
                 float* __restrict__ out)
{
    __shared__ float sg[DIM];
    __shared__ float r0[DIM], r1[DIM];
    const int r = blockIdx.x;
    const int c = threadIdx.x;

    sg[c] = G[r * DIM + c];
    __syncthreads();

    float a = b1f[c];
    #pragma unroll 8
    for (int k = 0; k < DIM; ++k)
        a = fmaf(sg[k], w1[k * DIM + c], a);
    float g2 = fmaxf(a, 0.f);
    r0[c] = g2 * w2[c * 2];
    r1[c] = g2 * w2[c * 2 + 1];
    __syncthreads();

    for (int off = 64; off > 0; off >>= 1) {
        if (c < off) { r0[c] += r0[c + off]; r1[c] += r1[c + off]; }
        __syncthreads();
    }
    if (c == 0) {
        out[r * 2]     = r0[0] + b2f[0];
        out[r * 2 + 1] = r1[0] + b2f[1];
    }
}

// ---------------------------------------------------------------------------
extern "C" void kernel_launch(void* const* d_in, const int* in_sizes, int n_in,
                              void* d_out, int out_size, void* d_ws, size_t ws_size,
                              hipStream_t stream)
{
    const float* x    = (const float*)d_in[0];
    const int*   ei   = (const int*)d_in[1];
    const int*   src  = ei;
    const int*   dst  = ei + N_EDGES;
    const int*   batch= (const int*)d_in[2];
    const float* w1_1 = (const float*)d_in[3];
    const float* b1_1 = (const float*)d_in[4];
    const float* bn1g = (const float*)d_in[5];
    const float* bn1b = (const float*)d_in[6];
    const float* bn1m = (const float*)d_in[7];
    const float* bn1v = (const float*)d_in[8];
    const float* w1_2 = (const float*)d_in[9];
    const float* b1_2 = (const float*)d_in[10];
    const float* w2_1 = (const float*)d_in[11];
    const float* b2_1 = (const float*)d_in[12];
    const float* bn2g = (const float*)d_in[13];
    const float* bn2b = (const float*)d_in[14];
    const float* bn2m = (const float*)d_in[15];
    const float* bn2v = (const float*)d_in[16];
    const float* w2_2 = (const float*)d_in[17];
    const float* b2_2 = (const float*)d_in[18];
    const float* lin1w= (const float*)d_in[19];
    const float* lin1b= (const float*)d_in[20];
    const float* lin2w= (const float*)d_in[21];
    const float* lin2b= (const float*)d_in[22];

    const size_t NBE  = (size_t)N_NODES * DIM;     // 6.4M
    const size_t NBEP = NBE + DIM;                 // + zero pad row
    __hip_bfloat16* xb = (__hip_bfloat16*)d_ws;    // NBEP bf16
    __hip_bfloat16* Ab = xb + NBEP;                // NBE bf16 (agg)
    __hip_bfloat16* Hb = Ab + NBE;                 // NBEP bf16 (mlp1 out)
    __hip_bfloat16* Wt = Hb + NBEP;                // 4 * 16384 bf16
    float* G  = (float*)(Wt + 4 * 16384);
    int* rowbeg = (int*)(G + NUM_GRAPHS * DIM);    // N_NODES
    int* rowend = rowbeg + N_NODES;                // N_NODES
    int* bcur   = rowend + N_NODES;                // NBUCK
    unsigned int* bedge = (unsigned int*)(bcur + NBUCK + 1);       // NBUCK*CAP
    unsigned short* elist = (unsigned short*)(bedge + (size_t)NBUCK * CAP);

    const int gather_grid = N_NODES / 4;               // 12500
    const int mlp_grid    = (N_NODES + 63) / 64;       // 782

    // ---- 0: zero bucket cursors (1.6 KB) ----
    hipMemsetAsync(bcur, 0, NBUCK * sizeof(int), stream);

    // ---- 1: prep (scatter || x-convert || w-convert || pad-zero) ----
    prep_kernel<<<PREP_GRID, 512, 0, stream>>>(
        x, xb, w1_1, w1_2, w2_1, w2_2, Wt, Hb, src, dst, bcur, bedge);

    // ---- 2: padded CSR finalize (+ G zeroing) ----
    bcsr_kernel<<<NBUCK, 256, 0, stream>>>(bedge, bcur, rowbeg, rowend, elist, G);

    // ---- 3-4: conv1 ----
    gather_agg_kernel<<<gather_grid, 256, 0, stream>>>(xb, rowbeg, rowend, elist, Ab);
    mlp_kernel<0><<<mlp_grid, 256, 0, stream>>>(
        Ab, Wt, Wt + 16384, b1_1, bn1g, bn1b, bn1m, bn1v, b1_2, Hb,
        batch, G, N_NODES);

    // ---- 5-6: conv2 (pool fused into MLP epilogue) ----
    gather_agg_kernel<<<gather_grid, 256, 0, stream>>>(Hb, rowbeg, rowend, elist, Ab);
    mlp_kernel<1><<<mlp_grid, 256, 0, stream>>>(
        Ab, Wt + 2 * 16384, Wt + 3 * 16384, b2_1, bn2g, bn2b, bn2m, bn2v, b2_2,
        (__hip_bfloat16*)nullptr, batch, G, N_NODES);

    // ---- 7: head ----
    head_kernel<<<NUM_GRAPHS, 128, 0, stream>>>(
        G, lin1w, lin1b, lin2w, lin2b, (float*)d_out);
}